// Round 7
// baseline (185.334 us; speedup 1.0000x reference)
//
#include <hip/hip_runtime.h>
#include <stdint.h>

// NCA step v7: wave-autonomous 8x8 tiles, ZERO barriers. Each wave owns a
// private 10x10 halo + r1 slice of LDS (time-overlaid), computes conv +
// MLP (MFMA, M=64) + epilogue independently -> phases of different waves
// overlap instead of marching in lockstep (v6: no pipe above 30%).
// B=8, C=20, H=W=256, HID=128, K_in=60 (pad 64), steps=4.

#define Bsz 8
#define Cn  20
#define Hn  256
#define Wn  256
#define HW  (Hn*Wn)

typedef float  f32x4  __attribute__((ext_vector_type(4)));
typedef __bf16 bf16x8 __attribute__((ext_vector_type(8)));
typedef __bf16 bf16x4 __attribute__((ext_vector_type(4)));
typedef short  s16x8  __attribute__((ext_vector_type(8)));

// Threefry-2x32, 20 rounds (verified r1: matches jax threefry_partitionable).
__device__ __host__ __forceinline__ void tf2x32(uint32_t k0, uint32_t k1,
                                                uint32_t x0, uint32_t x1,
                                                uint32_t& o0, uint32_t& o1) {
  uint32_t ks2 = k0 ^ k1 ^ 0x1BD11BDAu;
  x0 += k0; x1 += k1;
#define TFR(r) { x0 += x1; x1 = (x1 << (r)) | (x1 >> (32 - (r))); x1 ^= x0; }
  TFR(13) TFR(15) TFR(26) TFR(6)
  x0 += k1;  x1 += ks2 + 1u;
  TFR(17) TFR(29) TFR(16) TFR(24)
  x0 += ks2; x1 += k0 + 2u;
  TFR(13) TFR(15) TFR(26) TFR(6)
  x0 += k0;  x1 += k1 + 3u;
  TFR(17) TFR(29) TFR(16) TFR(24)
  x0 += k1;  x1 += ks2 + 4u;
  TFR(13) TFR(15) TFR(26) TFR(6)
  x0 += ks2; x1 += k0 + 5u;
#undef TFR
  o0 = x0; o1 = x1;
}

__device__ __forceinline__ f32x4 mfma16(bf16x8 a, bf16x8 b, f32x4 c) {
  return __builtin_amdgcn_mfma_f32_16x16x32_bf16(
      __builtin_bit_cast(s16x8, a), __builtin_bit_cast(s16x8, b), c, 0, 0, 0);
}

// W1p: GEMM1 B-fragments. i = (((ch*2+nt)*2+kb)*64 + l)*8 + e:
//   j = ch*32+nt*16+(l&15), k = kb*32+(l>>4)*8+e  -> W1[j][k] (k<60 else 0)
// W2p: GEMM2 A-fragments (A = W2, m = channel). i = ((mt*4+kb)*64+l)*8+e:
//   ch = mt*16+(l&15), j = kb*32+(l>>4)*8+e -> W2[ch][j] for 3<=ch<20 else 0
__global__ void pack_weights(const float* __restrict__ W1, const float* __restrict__ W2,
                             __bf16* __restrict__ W1p, __bf16* __restrict__ W2p) {
  int t = blockIdx.x * 256 + threadIdx.x;
  for (int i = t; i < 128 * 64; i += gridDim.x * 256) {
    int e = i & 7, l = (i >> 3) & 63, kb = (i >> 9) & 1, nt = (i >> 10) & 1, ch = i >> 11;
    int j = ch * 32 + nt * 16 + (l & 15);
    int k = kb * 32 + (l >> 4) * 8 + e;
    W1p[i] = (k < 60) ? (__bf16)W1[j * 60 + k] : (__bf16)0.f;
  }
  for (int i = t; i < 2 * 4 * 64 * 8; i += gridDim.x * 256) {
    int e = i & 7, l = (i >> 3) & 63, kb = (i >> 9) & 3, mt = (i >> 11) & 1;
    int ch = mt * 16 + (l & 15);
    int j  = kb * 32 + (l >> 4) * 8 + e;
    W2p[i] = (ch >= 3 && ch < Cn) ? (__bf16)W2[ch * 128 + j] : (__bf16)0.f;
  }
}

template <bool PRE>
__global__ __launch_bounds__(256, 4) void nca_step(
    const float* __restrict__ xin, float* __restrict__ xout,
    const float* __restrict__ wf1, const float* __restrict__ wf2,
    const float* __restrict__ W1, const float* __restrict__ b1,
    const float* __restrict__ W2,
    const __bf16* __restrict__ W1b, const __bf16* __restrict__ W2b,
    uint32_t ka, uint32_t kb_key) {

  // 4 waves x 2560 bf16 (5120 B) wave-PRIVATE slices, time-overlaid:
  //   early: halo tile [100 px][24 ch] bf16 (4800 B)
  //   late : r1 [64 rows][40 cols] bf16 (5120 B) -- perc chunks / H chunks
  // No cross-wave sharing -> no __syncthreads anywhere.
  __shared__ __align__(16) __bf16 smem[4 * 2560];

  const int tid = threadIdx.x;
  const int w = tid >> 6, l = tid & 63;
  __bf16* lds = smem + w * 2560;

  // XCD swizzle: round-robin dispatch -> XCD k handles batch image k.
  const int lin = (blockIdx.z * 16 + blockIdx.y) * 16 + blockIdx.x;
  const int swzb = (lin & 7) * 256 + (lin >> 3);
  const int b  = swzb >> 8;
  const int by = ((swzb >> 4) & 15) * 16;
  const int bx = (swzb & 15) * 16;
  // wave quadrant of the block's 16x16 region -> 8x8 tile origin
  const int by0 = by + (w >> 1) * 8;
  const int bx0 = bx + (w & 1) * 8;

  const float* __restrict__ xb = xin + (size_t)b * Cn * HW;

  // ---- Stage 10x10 halo (reflect) as bf16, channel-interleaved, wave-local ----
#pragma unroll
  for (int s = 0; s < 2; ++s) {
    int h = l + s * 64;
    if (h < 100) {
      int hy = h / 10, hx = h - hy * 10;
      int gy = by0 - 1 + hy; gy = (gy < 0) ? -gy : ((gy >= Hn) ? 2 * Hn - 2 - gy : gy);
      int gx = bx0 - 1 + hx; gx = (gx < 0) ? -gx : ((gx >= Wn) ? 2 * Wn - 2 - gx : gx);
      const float* sp = xb + (size_t)gy * Wn + gx;
      bf16x8 q0, q1; bf16x4 q2;
#pragma unroll
      for (int c = 0; c < 8; ++c)  q0[c] = (__bf16)sp[(size_t)c * HW];
#pragma unroll
      for (int c = 0; c < 8; ++c)  q1[c] = (__bf16)sp[(size_t)(c + 8) * HW];
#pragma unroll
      for (int c = 0; c < 4; ++c)  q2[c] = (__bf16)sp[(size_t)(c + 16) * HW];
      __bf16* wp = lds + h * 24;
      *(bf16x8*)(wp)      = q0;
      *(bf16x8*)(wp + 8)  = q1;
      *(bf16x4*)(wp + 16) = q2;
    }
  }

  // Fire mask in the load shadow: lane l owns pixel px=l (y=l>>3, x=l&7).
  const int py = l >> 3, px_ = l & 7;
  uint32_t y0, y1;
  tf2x32(ka, kb_key, 0u, (uint32_t)((b * Hn + by0 + py) * Wn + bx0 + px_), y0, y1);
  const unsigned long long fmask = __ballot(((y0 ^ y1) & 0x80000000u) == 0u);

  // ---- Depthwise conv (fp32 math, bf16 taps); own pixel only ----
  float a1[Cn], a2[Cn];
#pragma unroll
  for (int c = 0; c < Cn; ++c) { a1[c] = 0.f; a2[c] = 0.f; }
  bf16x8 id0, id1; bf16x4 id2;  // center tap = identity part of perc

#pragma unroll
  for (int ky = 0; ky < 3; ++ky)
#pragma unroll
    for (int kx = 0; kx < 3; ++kx) {
      const __bf16* tp = lds + ((py + ky) * 10 + px_ + kx) * 24;
      bf16x8 t0 = *(const bf16x8*)(tp);
      bf16x8 t1 = *(const bf16x8*)(tp + 8);
      bf16x4 t2 = *(const bf16x4*)(tp + 16);
      if (ky == 1 && kx == 1) { id0 = t0; id1 = t1; id2 = t2; }
      const int tap = ky * 3 + kx;
#pragma unroll
      for (int c = 0; c < 8; ++c) {
        float v = (float)t0[c];
        a1[c] = fmaf(wf1[c * 9 + tap], v, a1[c]);
        a2[c] = fmaf(wf2[c * 9 + tap], v, a2[c]);
      }
#pragma unroll
      for (int c = 0; c < 8; ++c) {
        float v = (float)t1[c];
        a1[c + 8] = fmaf(wf1[(c + 8) * 9 + tap], v, a1[c + 8]);
        a2[c + 8] = fmaf(wf2[(c + 8) * 9 + tap], v, a2[c + 8]);
      }
#pragma unroll
      for (int c = 0; c < 4; ++c) {
        float v = (float)t2[c];
        a1[c + 16] = fmaf(wf1[(c + 16) * 9 + tap], v, a1[c + 16]);
        a2[c + 16] = fmaf(wf2[(c + 16) * 9 + tap], v, a2[c + 16]);
      }
    }

  // ---- Pack perc -> r1 (time-shared 32-k chunks), load A-fragments (M=64) ----
  const int g4 = l >> 4, c16 = l & 15;

  bf16x8 af[4][2];
#pragma unroll
  for (int kb = 0; kb < 2; ++kb) {
#pragma unroll
    for (int g2 = 0; g2 < 4; ++g2) {
      bf16x8 pk;
#pragma unroll
      for (int e = 0; e < 8; ++e) {
        const int k = kb * 32 + g2 * 8 + e;
        __bf16 v;
        if      (k < 8)  v = id0[k];
        else if (k < 16) v = id1[k - 8];
        else if (k < 20) v = id2[k - 16];
        else if (k < 40) v = (__bf16)a1[k - 20];
        else if (k < 60) v = (__bf16)a2[k - 40];
        else             v = (__bf16)0.f;
        pk[e] = v;
      }
      *(bf16x8*)(lds + l * 40 + g2 * 8) = pk;   // own row l (overlays halo)
    }
    // same-wave LDS ordering: all lanes' writes precede these reads
#pragma unroll
    for (int mt = 0; mt < 4; ++mt)
      af[mt][kb] = *(const bf16x8*)(lds + (mt * 16 + c16) * 40 + g4 * 8);
  }

  // bias preload: biasv[q] = b1[q*16 + c16]
  float biasv[8];
#pragma unroll
  for (int q = 0; q < 8; ++q) biasv[q] = b1[q * 16 + c16];

  // ---- GEMM chunks: per 32 j's: GEMM1 -> H chunk (LDS) -> GEMM2 (swapped) ----
  const f32x4 zero4 = {0.f, 0.f, 0.f, 0.f};
  f32x4 acc2[2][4];   // [mt: ch 0..15 / 16..31][nt: 16-px groups of the 64 px]
#pragma unroll
  for (int mt = 0; mt < 2; ++mt)
#pragma unroll
    for (int nt = 0; nt < 4; ++nt) acc2[mt][nt] = zero4;

  const bf16x8* w1v = (const bf16x8*)W1b;
  const bf16x8* w2v = (const bf16x8*)W2b;

  for (int ch4 = 0; ch4 < 4; ++ch4) {
    // GEMM1 chunk: H[64 x 32j] = perc @ W1_chunk^T
#pragma unroll
    for (int nt = 0; nt < 2; ++nt) {
      bf16x8 bw0, bw1;
      if constexpr (PRE) {
        bw0 = w1v[((ch4 * 2 + nt) * 2 + 0) * 64 + l];
        bw1 = w1v[((ch4 * 2 + nt) * 2 + 1) * 64 + l];
      } else {
        const int j = ch4 * 32 + nt * 16 + c16;
        const float* rp = W1 + j * 60;
#pragma unroll
        for (int kb = 0; kb < 2; ++kb) {
          int ks = kb * 32 + g4 * 8;
          f32x4 lo = *(const f32x4*)(rp + ks);
          int ks2 = (ks == 56) ? 52 : ks + 4;
          f32x4 hi = *(const f32x4*)(rp + ks2);
          hi = (ks == 56) ? zero4 : hi;
          bf16x8 pk;
#pragma unroll
          for (int e = 0; e < 4; ++e) { pk[e] = (__bf16)lo[e]; pk[e + 4] = (__bf16)hi[e]; }
          if (kb == 0) bw0 = pk; else bw1 = pk;
        }
      }
      f32x4 a[4];
#pragma unroll
      for (int mt = 0; mt < 4; ++mt) {
        a[mt] = mfma16(af[mt][0], bw0, zero4);
        a[mt] = mfma16(af[mt][1], bw1, a[mt]);
      }
      const float bias = biasv[ch4 * 2 + nt];
#pragma unroll
      for (int mt = 0; mt < 4; ++mt)
#pragma unroll
        for (int r = 0; r < 4; ++r) {
          float hv = fmaxf(a[mt][r] + bias, 0.f);
          lds[(mt * 16 + g4 * 4 + r) * 40 + nt * 16 + c16] = (__bf16)hv;
        }
    }
    // GEMM2 (swapped): dx[ch][px] += W2_chunk @ H_chunk^T
    bf16x8 wa[2];
#pragma unroll
    for (int mt = 0; mt < 2; ++mt) {
      if constexpr (PRE) {
        wa[mt] = w2v[(mt * 4 + ch4) * 64 + l];
      } else {
        const int chl = mt * 16 + c16;
        bf16x8 pk;
        if (chl >= 3 && chl < Cn) {
          const float* rp2 = W2 + (size_t)chl * 128 + ch4 * 32 + g4 * 8;
          f32x4 lo = *(const f32x4*)(rp2);
          f32x4 hi = *(const f32x4*)(rp2 + 4);
#pragma unroll
          for (int e = 0; e < 4; ++e) { pk[e] = (__bf16)lo[e]; pk[e + 4] = (__bf16)hi[e]; }
        } else {
#pragma unroll
          for (int e = 0; e < 8; ++e) pk[e] = (__bf16)0.f;
        }
        wa[mt] = pk;
      }
    }
#pragma unroll
    for (int nt = 0; nt < 4; ++nt) {
      // B-fragment: lane holds H[px = nt*16+(l&15)][j-octet (l>>4)*8]
      bf16x8 hb = *(const bf16x8*)(lds + (nt * 16 + c16) * 40 + g4 * 8);
#pragma unroll
      for (int mt = 0; mt < 2; ++mt)
        acc2[mt][nt] = mfma16(wa[mt], hb, acc2[mt][nt]);
    }
  }

  // ---- Epilogue: D lane layout = (px = nt*16+(l&15), ch = mt*16+g4*4+r).
  // W2 rows <3 / >=20 are zero-padded -> image channels pass through exactly.
  float* __restrict__ ob = xout + (size_t)b * Cn * HW;
#pragma unroll
  for (int nt = 0; nt < 4; ++nt) {
    const int pxl = nt * 16 + c16;                         // pixel 0..63 in tile
    const int gy = by0 + (pxl >> 3), gx = bx0 + (pxl & 7);
    const size_t pix = (size_t)gy * Wn + gx;
    const float fire = ((fmask >> pxl) & 1ull) ? 1.f : 0.f;
#pragma unroll
    for (int mt = 0; mt < 2; ++mt)
#pragma unroll
      for (int r = 0; r < 4; ++r) {
        const int ch = mt * 16 + g4 * 4 + r;
        if (ch < Cn) {
          const size_t off = (size_t)ch * HW + pix;
          ob[off] = xb[off] + acc2[mt][nt][r] * fire;
        }
      }
  }
}

extern "C" void kernel_launch(void* const* d_in, const int* in_sizes, int n_in,
                              void* d_out, int out_size, void* d_ws, size_t ws_size,
                              hipStream_t stream) {
  const float* x   = (const float*)d_in[0];
  const float* wf1 = (const float*)d_in[1];
  const float* wf2 = (const float*)d_in[2];
  const float* W1  = (const float*)d_in[3];
  const float* b1  = (const float*)d_in[4];
  const float* W2  = (const float*)d_in[5];
  const int steps = 4;

  float* out = (float*)d_out;
  float* ws0 = (float*)d_ws;                       // 41,943,040 B ping buffer
  const size_t PING = (size_t)Bsz * Cn * HW * 4;
  const size_t WNEED = PING + (128 * 64 + 2 * 4 * 64 * 8) * sizeof(__bf16);
  const bool pre = (ws_size >= WNEED);
  __bf16* W1p = pre ? (__bf16*)((char*)d_ws + PING) : nullptr;
  __bf16* W2p = pre ? W1p + 128 * 64 : nullptr;

  if (pre) pack_weights<<<8, 256, 0, stream>>>(W1, W2, W1p, W2p);

  dim3 grid(16, 16, Bsz);
  dim3 blk(256);

  const float* src = x;
  for (int s = 0; s < steps; ++s) {
    uint32_t ka, kb;
    tf2x32(0u, 42u, 0u, (uint32_t)s, ka, kb);      // fold_in(key(42), s)
    float* dst = (((steps - s) % 2) == 1) ? out : ws0;
    if (pre) nca_step<true ><<<grid, blk, 0, stream>>>(src, dst, wf1, wf2, W1, b1, W2, W1p, W2p, ka, kb);
    else     nca_step<false><<<grid, blk, 0, stream>>>(src, dst, wf1, wf2, W1, b1, W2, W1p, W2p, ka, kb);
    src = dst;
  }
}